// Round 3
// baseline (328.111 us; speedup 1.0000x reference)
//
#include <hip/hip_runtime.h>
#include <hip/hip_bf16.h>

// Shapes: B=32 S=1024 D=256 V=50257 C=1000   (ALL float tensors are fp32; x int32)
// conv1: groups=256, Cin/g=1, Cout/g=6, K=7, pad=6 -> L1=1030; fold -> 768 ch
// kmax k1=515 -> tanh -> conv2: groups=128, Cin/g=6, Cout/g=14, K=5, pad=4 -> L2=519
// fold -> 896 ch -> kmax 4 -> tanh -> (32,3584) @ wf^T(1000,3584) + bf -> fp32 out
//
// Fused stage12: block = (b, r2). Conv2 group pair (2*r2, 2*r2+1) consumes conv1-folded
// channels r2*12..r2*12+11 = emb channels 4*r2..4*r2+3. Intermediate F lives in LDS.
// ws holds only H (32x3584 bf16 = 229 KB).

__device__ __forceinline__ float fast_tanh(float x) {
    float e = __expf(2.f * x);          // tanh = 1 - 2/(e^{2x}+1); saturates correctly at +-inf
    return 1.f - 2.f / (e + 1.f);
}

__device__ __forceinline__ unsigned fkey(float f) {
    unsigned u = __float_as_uint(f);
    return (u & 0x80000000u) ? ~u : (u | 0x80000000u);   // monotone order-preserving key
}

__device__ __forceinline__ unsigned short f2bf_rne(float f) {
    unsigned u = __float_as_uint(f);
    return (unsigned short)((u + 0x7fffu + ((u >> 16) & 1u)) >> 16);
}

// ---------------- Fused: gather + conv1 + fold + kmax(515) + tanh + conv2 + fold + kmax(4) + tanh ----
// grid = 32*64 blocks (b, r2), 896 threads = 14 waves
__global__ __launch_bounds__(896) void stage12_kernel(
    const int* __restrict__ x, const float* __restrict__ emb,
    const float* __restrict__ w1, const float* __restrict__ b1,
    const float* __restrict__ w2, const float* __restrict__ b2,
    __hip_bfloat16* __restrict__ H)
{
    __shared__ __align__(16) float e[4 * 1104];   // 4 emb channels, padded seq (idx = l+6)
    __shared__ __align__(16) float F[12 * 584];   // 12 folded conv1 rows; F[i][4+pos], pos in [0,515)
    const int b = blockIdx.x >> 6;
    const int r2 = blockIdx.x & 63;
    const int tid = threadIdx.x;

    // Phase A: zero F (left pad [0,4) and tail [519,584) must be 0), gather 4 emb channels
    for (int i = tid; i < 12 * 584; i += 896) F[i] = 0.f;
    for (int idx = tid; idx < 1104; idx += 896) {
        int l = idx - 6;
        float4 v = {0.f, 0.f, 0.f, 0.f};
        if (l >= 0 && l < 1024) {
            int tok = x[(b << 10) + l];
            v = *(const float4*)(emb + (size_t)tok * 256 + (r2 << 2));  // 16B aligned
        }
        e[0 * 1104 + idx] = v.x;
        e[1 * 1104 + idx] = v.y;
        e[2 * 1104 + idx] = v.z;
        e[3 * 1104 + idx] = v.w;
    }
    __syncthreads();

    const int w = tid >> 6;
    const int lane = tid & 63;

    // Phase B: waves 0..11 -> folded conv1 channel i=w, radix-select 515, tanh -> F
    if (w < 12) {
        const int half = (w >= 6) ? 1 : 0;
        const int f = w - half * 6;
        const int r = 2 * r2 + half;                  // emb-channel pair index
        const float* ep0 = e + (2 * half) * 1104;     // emb channel 2r   (= 4*r2 + 2*half)
        const float* ep1 = ep0 + 1104;                // emb channel 2r+1
        const int c0 = (2 * r) * 6 + f;               // conv1 channel for d=2r
        const int c1 = c0 + 6;                        // conv1 channel for d=2r+1
        float wA[7], wB[7];
#pragma unroll
        for (int t = 0; t < 7; ++t) { wA[t] = w1[c0 * 7 + t]; wB[t] = w1[c1 * 7 + t]; }
        const float bias = b1[c0] + b1[c1];

        const int pos0 = lane * 17;                   // 17 contiguous outputs per lane (64*17>=1030)
        float eb0[23], eb1[23];
#pragma unroll
        for (int i = 0; i < 23; ++i) { eb0[i] = ep0[pos0 + i]; eb1[i] = ep1[pos0 + i]; }

        float v[17]; unsigned key[17];
#pragma unroll
        for (int j = 0; j < 17; ++j) {
            float a = bias;
#pragma unroll
            for (int t = 0; t < 7; ++t) a += eb0[j + t] * wA[t] + eb1[j + t] * wB[t];
            v[j] = a;
            key[j] = (pos0 + j < 1030) ? fkey(a) : 0u;   // pads: key 0 (below any real key)
        }

        // exact radix-select of the 515th-largest key
        unsigned T = 0u;
        for (int bit = 31; bit >= 0; --bit) {
            unsigned cand = T | (1u << bit);
            int cnt = 0;
#pragma unroll
            for (int j = 0; j < 17; ++j) cnt += (int)__popcll(__ballot(key[j] >= cand));
            if (cnt >= 515) T = cand;
        }

        // order-preserving compaction: keep all >T plus first (515-#gt) ==T in index order
        const unsigned long long lm = (1ull << lane) - 1ull;
        int gt_tot = 0, gt_run = 0, eq_run = 0;
#pragma unroll
        for (int j = 0; j < 17; ++j) {
            unsigned long long bg = __ballot(key[j] > T);
            unsigned long long be = __ballot(key[j] == T);
            gt_tot += (int)__popcll(bg);
            gt_run += (int)__popcll(bg & lm);
            eq_run += (int)__popcll(be & lm);
        }
        const int q = 515 - gt_tot;                    // #eq to keep (q >= 1 by construction)
        float* Frow = F + w * 584;
#pragma unroll
        for (int j = 0; j < 17; ++j) {
            bool isgt = key[j] > T;
            bool iseq = key[j] == T;
            int pos = gt_run + (eq_run < q ? eq_run : q);
            if (isgt || (iseq && eq_run < q)) Frow[4 + pos] = fast_tanh(v[j]);
            gt_run += isgt ? 1 : 0;
            eq_run += iseq ? 1 : 0;
        }
    }
    __syncthreads();

    // Phase C: wave w -> folded conv2 channel j=w (14 waves), kmax4 + tanh -> H
    {
        const int j = w;
        const int base = lane * 9;                     // 9 outputs per lane, 64*9=576 >= 519
        const float bias2 = b2[(2 * r2) * 14 + j] + b2[(2 * r2 + 1) * 14 + j];
        float acc[9];
#pragma unroll
        for (int jj = 0; jj < 9; ++jj) acc[jj] = bias2;

#pragma unroll
        for (int i = 0; i < 12; ++i) {
            const float* Fr = F + i * 584 + base;      // y[p] = sum_t F[i][p+t] (4-left-padded)
            float eb[13];
#pragma unroll
            for (int qq = 0; qq < 13; ++qq) eb[qq] = Fr[qq];
            const int cg = 2 * r2 + ((i >= 6) ? 1 : 0);
            const int ii = (i >= 6) ? (i - 6) : i;
            const float* wq = w2 + (size_t)((cg * 14 + j) * 6 + ii) * 5;
#pragma unroll
            for (int t = 0; t < 5; ++t) {
                float wv = wq[t];
#pragma unroll
                for (int jj = 0; jj < 9; ++jj) acc[jj] += eb[jj + t] * wv;
            }
        }

        float vv[9];
#pragma unroll
        for (int jj = 0; jj < 9; ++jj) vv[jj] = (base + jj < 519) ? acc[jj] : -INFINITY;
        float sv[4]; int si[4];
#pragma unroll
        for (int it = 0; it < 4; ++it) {
            float m = vv[0]; int mi = base;
#pragma unroll
            for (int jj = 1; jj < 9; ++jj) { if (vv[jj] > m) { m = vv[jj]; mi = base + jj; } }
#pragma unroll
            for (int d = 1; d < 64; d <<= 1) {
                float om = __shfl_xor(m, d, 64);
                int omi = __shfl_xor(mi, d, 64);
                if (om > m || (om == m && omi < mi)) { m = om; mi = omi; }
            }
            sv[it] = m; si[it] = mi;
            int lj = mi - base;                        // only in [0,9) on the winning lane
#pragma unroll
            for (int jj = 0; jj < 9; ++jj) if (jj == lj) vv[jj] = -INFINITY;
        }
        // sort the 4 by original index ascending (order-preserving kmax)
#define CSWAP(a, bq) { if (si[a] > si[bq]) { int ti = si[a]; si[a] = si[bq]; si[bq] = ti; \
                                             float tv = sv[a]; sv[a] = sv[bq]; sv[bq] = tv; } }
        CSWAP(0, 1) CSWAP(2, 3) CSWAP(0, 2) CSWAP(1, 3) CSWAP(1, 2)
#undef CSWAP
        if (lane == 0) {
            __hip_bfloat16* op = H + (size_t)b * 3584 + (r2 * 14 + j) * 4;
#pragma unroll
            for (int k = 0; k < 4; ++k) op[k] = __float2bfloat16(fast_tanh(sv[k]));
        }
    }
}

// ---------------- Stage 3: (32x3584) @ wf^T (3584x1000) + bf via MFMA ----------------
// wf is fp32, converted RNE->bf16 in-register. Both 16-row m-tiles per block -> wf read once.
typedef __attribute__((ext_vector_type(8))) short short8;
typedef __attribute__((ext_vector_type(4))) float f32x4;

__global__ __launch_bounds__(256) void stage3_kernel(
    const __hip_bfloat16* __restrict__ Hb, const float* __restrict__ wf,
    const float* __restrict__ bfv, float* __restrict__ out)
{
    __shared__ __align__(16) float sred[2 * 4 * 256];
    const int nt = blockIdx.x;           // n-tile of 16 cols, 63 tiles
    const int w = threadIdx.x >> 6, lane = threadIdx.x & 63;
    const int row = lane & 15, quad = lane >> 4;
    const int c = nt * 16 + row;
    const bool cvalid = (c < 1000);
    const __hip_bfloat16* ap0 = Hb + (size_t)row * 3584 + w * 896 + quad * 8;        // rows 0..15
    const __hip_bfloat16* ap1 = ap0 + (size_t)16 * 3584;                             // rows 16..31
    const float* bp = wf + (size_t)(cvalid ? c : 0) * 3584 + w * 896 + quad * 8;

    f32x4 acc0 = {0.f, 0.f, 0.f, 0.f};
    f32x4 acc1 = {0.f, 0.f, 0.f, 0.f};
#pragma unroll 4
    for (int it = 0; it < 28; ++it) {
        short8 a0 = *(const short8*)(ap0 + it * 32);
        short8 a1 = *(const short8*)(ap1 + it * 32);
        float4 p0 = *(const float4*)(bp + it * 32);
        float4 p1 = *(const float4*)(bp + it * 32 + 4);
        short8 bfr;
        bfr[0] = (short)f2bf_rne(p0.x); bfr[1] = (short)f2bf_rne(p0.y);
        bfr[2] = (short)f2bf_rne(p0.z); bfr[3] = (short)f2bf_rne(p0.w);
        bfr[4] = (short)f2bf_rne(p1.x); bfr[5] = (short)f2bf_rne(p1.y);
        bfr[6] = (short)f2bf_rne(p1.z); bfr[7] = (short)f2bf_rne(p1.w);
        if (!cvalid) bfr = short8{0, 0, 0, 0, 0, 0, 0, 0};
        acc0 = __builtin_amdgcn_mfma_f32_16x16x32_bf16(a0, bfr, acc0, 0, 0, 0);
        acc1 = __builtin_amdgcn_mfma_f32_16x16x32_bf16(a1, bfr, acc1, 0, 0, 0);
    }
#pragma unroll
    for (int r_ = 0; r_ < 4; ++r_) {
        sred[(0 * 4 + w) * 256 + lane * 4 + r_] = acc0[r_];
        sred[(1 * 4 + w) * 256 + lane * 4 + r_] = acc1[r_];
    }
    __syncthreads();
    if (threadIdx.x < 128) {
        const int mt = threadIdx.x >> 6;           // 0: rows 0..15, 1: rows 16..31
        const int l2 = threadIdx.x & 63;
        const int rr = l2 & 15, qq = l2 >> 4;
        const int cc = nt * 16 + rr;
        if (cc < 1000) {
#pragma unroll
            for (int r_ = 0; r_ < 4; ++r_) {
                const float* sp = sred + mt * 4 * 256;
                float s = sp[0 * 256 + l2 * 4 + r_] + sp[1 * 256 + l2 * 4 + r_]
                        + sp[2 * 256 + l2 * 4 + r_] + sp[3 * 256 + l2 * 4 + r_];
                int brow = mt * 16 + qq * 4 + r_;   // C/D: col=lane&15, row=quad*4+reg
                out[brow * 1000 + cc] = s + bfv[cc];
            }
        }
    }
}

extern "C" void kernel_launch(void* const* d_in, const int* in_sizes, int n_in,
                              void* d_out, int out_size, void* d_ws, size_t ws_size,
                              hipStream_t stream) {
    const int* x      = (const int*)d_in[0];
    const float* emb  = (const float*)d_in[1];
    const float* w1   = (const float*)d_in[2];
    const float* b1   = (const float*)d_in[3];
    const float* w2   = (const float*)d_in[4];
    const float* b2   = (const float*)d_in[5];
    const float* wf   = (const float*)d_in[6];
    const float* bfv  = (const float*)d_in[7];

    __hip_bfloat16* H = (__hip_bfloat16*)d_ws;    // 32*3584 bf16 = 229,376 B

    stage12_kernel<<<32 * 64, 896, 0, stream>>>(x, emb, w1, b1, w2, b2, H);
    stage3_kernel<<<63, 256, 0, stream>>>(H, wf, bfv, (float*)d_out);
}

// Round 4
// 290.761 us; speedup vs baseline: 1.1285x; 1.1285x over previous
//
#include <hip/hip_runtime.h>
#include <hip/hip_bf16.h>

// Shapes: B=32 S=1024 D=256 V=50257 C=1000   (float tensors fp32; x int32; out fp32)
// conv1: groups=256, Cin/g=1, Cout/g=6, K=7, pad=6 -> L1=1030; fold -> 768 ch
// kmax k1=515 -> tanh -> conv2: groups=128, Cin/g=6, Cout/g=14, K=5, pad=4 -> L2=519
// fold -> 896 ch -> kmax 4 -> tanh -> (32,3584) @ wf^T(1000,3584) + bf
//
// stage12 fused per (b, r2): conv2 group pair (2*r2,2*r2+1) consumes conv1-folded
// channels r2*12..r2*12+11 = emb channels 4*r2..4*r2+3; F kept in LDS.
// Round-4 fix: rolling windows + key-only radix state -> ~53 live VGPRs, no scratch
// spills (round 3 had 49 MB spill-writes/dispatch at VGPR_Count=64).

__device__ __forceinline__ float fast_tanh(float x) {
    float e = __expf(2.f * x);          // tanh = 1 - 2/(e^{2x}+1); saturates at +-inf
    return 1.f - 2.f / (e + 1.f);
}

__device__ __forceinline__ unsigned fkey(float f) {
    unsigned u = __float_as_uint(f);
    return (u & 0x80000000u) ? ~u : (u | 0x80000000u);   // monotone order-preserving key
}

__device__ __forceinline__ float fkey_inv(unsigned k) {   // exact inverse of fkey
    unsigned u = (k & 0x80000000u) ? (k ^ 0x80000000u) : ~k;
    return __uint_as_float(u);
}

__device__ __forceinline__ unsigned short f2bf_rne(float f) {
    unsigned u = __float_as_uint(f);
    return (unsigned short)((u + 0x7fffu + ((u >> 16) & 1u)) >> 16);
}

// ---------------- Fused: gather + conv1 + fold + kmax(515) + tanh + conv2 + fold + kmax(4) + tanh ----
// grid = 32*64 blocks (b, r2), 896 threads = 14 waves
__global__ __launch_bounds__(896) void stage12_kernel(
    const int* __restrict__ x, const float* __restrict__ emb,
    const float* __restrict__ w1, const float* __restrict__ b1,
    const float* __restrict__ w2, const float* __restrict__ b2,
    __hip_bfloat16* __restrict__ H)
{
    __shared__ __align__(16) float e[4 * 1104];   // 4 emb channels, padded seq (idx = l+6)
    __shared__ __align__(16) float F[12 * 584];   // folded conv1 rows; F[i][4+pos], pos in [0,515)
    const int b = blockIdx.x >> 6;
    const int r2 = blockIdx.x & 63;
    const int tid = threadIdx.x;

    // Phase A: zero F (left pad [0,4) and tail [519,584) must stay 0), gather 4 emb channels
    for (int i = tid; i < 12 * 584; i += 896) F[i] = 0.f;
    for (int idx = tid; idx < 1104; idx += 896) {
        int l = idx - 6;
        float4 v = {0.f, 0.f, 0.f, 0.f};
        if (l >= 0 && l < 1024) {
            int tok = x[(b << 10) + l];
            v = *(const float4*)(emb + (size_t)tok * 256 + (r2 << 2));  // 16B aligned
        }
        e[0 * 1104 + idx] = v.x;
        e[1 * 1104 + idx] = v.y;
        e[2 * 1104 + idx] = v.z;
        e[3 * 1104 + idx] = v.w;
    }
    __syncthreads();

    const int w = tid >> 6;
    const int lane = tid & 63;

    // Phase B: waves 0..11 -> folded conv1 channel i=w, radix-select 515, tanh -> F
    if (w < 12) {
        const int half = (w >= 6) ? 1 : 0;
        const int f = w - half * 6;
        const float* ep0 = e + (2 * half) * 1104;     // emb channel 4*r2 + 2*half
        const float* ep1 = ep0 + 1104;
        const int c0 = __builtin_amdgcn_readfirstlane((2 * (2 * r2 + half)) * 6 + f);
        const int c1 = c0 + 6;
        float wA[7], wB[7];
#pragma unroll
        for (int t = 0; t < 7; ++t) { wA[t] = w1[c0 * 7 + t]; wB[t] = w1[c1 * 7 + t]; }
        const float bias = b1[c0] + b1[c1];

        const int pos0 = lane * 17;                   // 17 contiguous outputs/lane (64*17>=1030)
        float a0[7], a1[7];                           // rolling conv window
#pragma unroll
        for (int t = 0; t < 7; ++t) { a0[t] = ep0[pos0 + t]; a1[t] = ep1[pos0 + t]; }

        unsigned key[17];
#pragma unroll
        for (int j = 0; j < 17; ++j) {
            float a = bias;
#pragma unroll
            for (int t = 0; t < 7; ++t) a += a0[t] * wA[t] + a1[t] * wB[t];
            key[j] = (pos0 + j < 1030) ? fkey(a) : 0u;   // pads: key 0 (below any real key)
            if (j < 16) {
#pragma unroll
                for (int t = 0; t < 6; ++t) { a0[t] = a0[t + 1]; a1[t] = a1[t + 1]; }
                a0[6] = ep0[pos0 + j + 7];
                a1[6] = ep1[pos0 + j + 7];
            }
        }

        // exact radix-select of the 515th-largest key
        unsigned T = 0u;
        for (int bit = 31; bit >= 0; --bit) {
            unsigned cand = T | (1u << bit);
            int cnt = 0;
#pragma unroll
            for (int j = 0; j < 17; ++j) cnt += (int)__popcll(__ballot(key[j] >= cand));
            if (cnt >= 515) T = cand;
        }

        // order-preserving compaction: keep all >T plus first (515-#gt) ==T in index order
        const unsigned long long lm = (1ull << lane) - 1ull;
        int gt_tot = 0, gt_run = 0, eq_run = 0;
#pragma unroll
        for (int j = 0; j < 17; ++j) {
            unsigned long long bg = __ballot(key[j] > T);
            unsigned long long be = __ballot(key[j] == T);
            gt_tot += (int)__popcll(bg);
            gt_run += (int)__popcll(bg & lm);
            eq_run += (int)__popcll(be & lm);
        }
        const int q = 515 - gt_tot;                    // #eq to keep (lowest index first)
        float* Frow = F + w * 584;
#pragma unroll
        for (int j = 0; j < 17; ++j) {
            bool isgt = key[j] > T;
            bool iseq = key[j] == T;
            int pos = gt_run + (eq_run < q ? eq_run : q);
            if (isgt || (iseq && eq_run < q)) Frow[4 + pos] = fast_tanh(fkey_inv(key[j]));
            gt_run += isgt ? 1 : 0;
            eq_run += iseq ? 1 : 0;
        }
    }
    __syncthreads();

    // Phase C: wave w -> folded conv2 channel j=w (14 waves), kmax4 + tanh -> H
    {
        const int j = w;
        const int base = lane * 9;                     // 9 outputs/lane, 64*9=576 >= 519
        const float bias2 = b2[(2 * r2) * 14 + j] + b2[(2 * r2 + 1) * 14 + j];
        float acc[9];
#pragma unroll
        for (int jj = 0; jj < 9; ++jj) acc[jj] = bias2;

#pragma unroll
        for (int i = 0; i < 12; ++i) {
            const float* Fr = F + i * 584 + base;      // y[p] = sum_t F[i][p+t] (4-left-padded)
            const int cg = 2 * r2 + ((i >= 6) ? 1 : 0);
            const int ii = (i >= 6) ? (i - 6) : i;
            const int widx = __builtin_amdgcn_readfirstlane(((cg * 14 + j) * 6 + ii) * 5);
            float wv[5];
#pragma unroll
            for (int t = 0; t < 5; ++t) wv[t] = w2[widx + t];
            float win[5];                              // rolling window over F row
#pragma unroll
            for (int t = 0; t < 5; ++t) win[t] = Fr[t];
#pragma unroll
            for (int jj = 0; jj < 9; ++jj) {
#pragma unroll
                for (int t = 0; t < 5; ++t) acc[jj] += win[t] * wv[t];
                if (jj < 8) {
#pragma unroll
                    for (int t = 0; t < 4; ++t) win[t] = win[t + 1];
                    win[4] = Fr[jj + 5];
                }
            }
        }

        float vv[9];
#pragma unroll
        for (int jj = 0; jj < 9; ++jj) vv[jj] = (base + jj < 519) ? acc[jj] : -INFINITY;
        float sv[4]; int si[4];
#pragma unroll
        for (int it = 0; it < 4; ++it) {
            float m = vv[0]; int mi = base;
#pragma unroll
            for (int jj = 1; jj < 9; ++jj) { if (vv[jj] > m) { m = vv[jj]; mi = base + jj; } }
#pragma unroll
            for (int d = 1; d < 64; d <<= 1) {
                float om = __shfl_xor(m, d, 64);
                int omi = __shfl_xor(mi, d, 64);
                if (om > m || (om == m && omi < mi)) { m = om; mi = omi; }
            }
            sv[it] = m; si[it] = mi;
            int lj = mi - base;
#pragma unroll
            for (int jj = 0; jj < 9; ++jj) if (jj == lj) vv[jj] = -INFINITY;
        }
#define CSWAP(a, bq) { if (si[a] > si[bq]) { int ti = si[a]; si[a] = si[bq]; si[bq] = ti; \
                                             float tv = sv[a]; sv[a] = sv[bq]; sv[bq] = tv; } }
        CSWAP(0, 1) CSWAP(2, 3) CSWAP(0, 2) CSWAP(1, 3) CSWAP(1, 2)
#undef CSWAP
        if (lane == 0) {
            __hip_bfloat16* op = H + (size_t)b * 3584 + (r2 * 14 + j) * 4;
#pragma unroll
            for (int k = 0; k < 4; ++k) op[k] = __float2bfloat16(fast_tanh(sv[k]));
        }
    }
}

// ---------------- Stage 3: (32x3584) @ wf^T (3584x1000) + bf via MFMA, K split 4 ways ----------------
typedef __attribute__((ext_vector_type(8))) short short8;
typedef __attribute__((ext_vector_type(4))) float f32x4;

__global__ __launch_bounds__(256) void bias_init_kernel(
    const float* __restrict__ bfv, float* __restrict__ out)
{
    int idx = blockIdx.x * 256 + threadIdx.x;
    if (idx < 32000) out[idx] = bfv[idx - (idx / 1000) * 1000];
}

// grid = 63 n-tiles * 4 k-chunks; each block does K range [kc*896, kc*896+896)
__global__ __launch_bounds__(256) void stage3_kernel(
    const __hip_bfloat16* __restrict__ Hb, const float* __restrict__ wf,
    float* __restrict__ out)
{
    __shared__ __align__(16) float sred[2 * 4 * 256];
    const int nt = blockIdx.x % 63;
    const int kc = blockIdx.x / 63;
    const int w = threadIdx.x >> 6, lane = threadIdx.x & 63;
    const int row = lane & 15, quad = lane >> 4;
    const int c = nt * 16 + row;
    const bool cvalid = (c < 1000);
    const int kofs = kc * 896 + w * 224 + quad * 8;
    const __hip_bfloat16* ap0 = Hb + (size_t)row * 3584 + kofs;          // batch rows 0..15
    const __hip_bfloat16* ap1 = ap0 + (size_t)16 * 3584;                 // batch rows 16..31
    const float* bp = wf + (size_t)(cvalid ? c : 0) * 3584 + kofs;

    f32x4 acc0 = {0.f, 0.f, 0.f, 0.f};
    f32x4 acc1 = {0.f, 0.f, 0.f, 0.f};
#pragma unroll
    for (int it = 0; it < 7; ++it) {
        short8 a0 = *(const short8*)(ap0 + it * 32);
        short8 a1 = *(const short8*)(ap1 + it * 32);
        float4 p0 = *(const float4*)(bp + it * 32);
        float4 p1 = *(const float4*)(bp + it * 32 + 4);
        short8 bfr;
        bfr[0] = (short)f2bf_rne(p0.x); bfr[1] = (short)f2bf_rne(p0.y);
        bfr[2] = (short)f2bf_rne(p0.z); bfr[3] = (short)f2bf_rne(p0.w);
        bfr[4] = (short)f2bf_rne(p1.x); bfr[5] = (short)f2bf_rne(p1.y);
        bfr[6] = (short)f2bf_rne(p1.z); bfr[7] = (short)f2bf_rne(p1.w);
        if (!cvalid) bfr = short8{0, 0, 0, 0, 0, 0, 0, 0};
        acc0 = __builtin_amdgcn_mfma_f32_16x16x32_bf16(a0, bfr, acc0, 0, 0, 0);
        acc1 = __builtin_amdgcn_mfma_f32_16x16x32_bf16(a1, bfr, acc1, 0, 0, 0);
    }
#pragma unroll
    for (int r_ = 0; r_ < 4; ++r_) {
        sred[(0 * 4 + w) * 256 + lane * 4 + r_] = acc0[r_];
        sred[(1 * 4 + w) * 256 + lane * 4 + r_] = acc1[r_];
    }
    __syncthreads();
    if (threadIdx.x < 128) {
        const int mt = threadIdx.x >> 6;           // 0: batch rows 0..15, 1: rows 16..31
        const int l2 = threadIdx.x & 63;
        const int rr = l2 & 15, qq = l2 >> 4;
        const int cc = nt * 16 + rr;
        if (cc < 1000) {
            const float* sp = sred + mt * 4 * 256;
#pragma unroll
            for (int r_ = 0; r_ < 4; ++r_) {
                float s = sp[0 * 256 + l2 * 4 + r_] + sp[1 * 256 + l2 * 4 + r_]
                        + sp[2 * 256 + l2 * 4 + r_] + sp[3 * 256 + l2 * 4 + r_];
                int brow = mt * 16 + qq * 4 + r_;   // C/D: col=lane&15, row=quad*4+reg
                atomicAdd(&out[brow * 1000 + cc], s);
            }
        }
    }
}

extern "C" void kernel_launch(void* const* d_in, const int* in_sizes, int n_in,
                              void* d_out, int out_size, void* d_ws, size_t ws_size,
                              hipStream_t stream) {
    const int* x      = (const int*)d_in[0];
    const float* emb  = (const float*)d_in[1];
    const float* w1   = (const float*)d_in[2];
    const float* b1   = (const float*)d_in[3];
    const float* w2   = (const float*)d_in[4];
    const float* b2   = (const float*)d_in[5];
    const float* wf   = (const float*)d_in[6];
    const float* bfv  = (const float*)d_in[7];

    __hip_bfloat16* H = (__hip_bfloat16*)d_ws;    // 32*3584 bf16 = 229,376 B

    bias_init_kernel<<<125, 256, 0, stream>>>(bfv, (float*)d_out);
    stage12_kernel<<<32 * 64, 896, 0, stream>>>(x, emb, w1, b1, w2, b2, H);
    stage3_kernel<<<63 * 4, 256, 0, stream>>>(H, wf, (float*)d_out);
}